// Round 2
// baseline (320.184 us; speedup 1.0000x reference)
//
#include <hip/hip_runtime.h>
#include <cstdint>
#include <cstddef>

// Problem constants
#define DM 1024   // d_model
#define NH 16     // heads
#define DH 64     // d_head
#define NB 2      // batch
#define SQ 2048   // seq len
#define MT (NB*SQ) // 4096 total rows

typedef float  f32x4 __attribute__((ext_vector_type(4)));
typedef short  s16x8 __attribute__((ext_vector_type(8)));
typedef short  s16x4 __attribute__((ext_vector_type(4)));

// fp32 -> bf16 bits, round-to-nearest-even (no __hip_bfloat16 dependency)
__device__ __forceinline__ unsigned short f2bf(float x) {
    unsigned int u = __float_as_uint(x);
    unsigned int lsb = (u >> 16) & 1u;
    u += 0x7fffu + lsb;
    return (unsigned short)(u >> 16);
}

// async global->LDS, 16 bytes per lane. LDS dest must be wave-uniform base + lane*16,
// which our chunk layouts guarantee (chunk index c = i*256 + tid, LDS offset = c*16).
__device__ __forceinline__ void gload16(const void* g, void* l) {
    __builtin_amdgcn_global_load_lds(
        (const __attribute__((address_space(1))) void*)g,
        (__attribute__((address_space(3))) void*)l,
        16, 0, 0);
}

// ---------------- cast kernel: fp32 -> bf16 (4 elems/thread) ----------------
__global__ __launch_bounds__(256) void castk(const float* __restrict__ in,
                                             unsigned short* __restrict__ out, int n) {
    int i = (blockIdx.x * 256 + threadIdx.x) * 4;
    if (i >= n) return;
    float4 a = *reinterpret_cast<const float4*>(in + i);
    s16x4 r;
    r[0] = (short)f2bf(a.x);
    r[1] = (short)f2bf(a.y);
    r[2] = (short)f2bf(a.z);
    r[3] = (short)f2bf(a.w);
    *reinterpret_cast<s16x4*>(out + i) = r;
}

// ---------------- GEMM core: C[m,n] = sum_k A[m,k]*B[n,k], 128x128 tile, BK=64 ----------------
// m97-style: global_load_lds width 16, single LDS buffer, 2 barriers/K-step,
// 4 waves in 2x2, each 64x64 = 4x4 fragments of 16x16x32 bf16 MFMA.
__device__ __forceinline__ void gemm_core(const unsigned short* __restrict__ A,
                                          const unsigned short* __restrict__ Bm,
                                          int m0, int n0, int t,
                                          unsigned short (*As)[64],
                                          unsigned short (*Bs)[64],
                                          f32x4 acc[4][4]) {
    const int lane = t & 63, w = t >> 6;
    const int wm = (w >> 1) * 64, wn = (w & 1) * 64;
    const int lo = lane & 15, hi = lane >> 4;

    for (int k0 = 0; k0 < DM; k0 += 64) {
        // stage A-tile (128x64) and B-tile (128x64): 1024 chunks of 16B each
#pragma unroll
        for (int i = 0; i < 4; i++) {
            int c = i * 256 + t;
            int r = c >> 3, col = (c & 7) * 8;
            gload16(A  + (size_t)(m0 + r) * DM + k0 + col, &As[r][col]);
            gload16(Bm + (size_t)(n0 + r) * DM + k0 + col, &Bs[r][col]);
        }
        asm volatile("s_waitcnt vmcnt(0)" ::: "memory");
        __syncthreads();

#pragma unroll
        for (int kk = 0; kk < 64; kk += 32) {
            s16x8 a[4], b[4];
#pragma unroll
            for (int mi = 0; mi < 4; mi++)
                a[mi] = *reinterpret_cast<const s16x8*>(&As[wm + mi * 16 + lo][kk + hi * 8]);
#pragma unroll
            for (int ni = 0; ni < 4; ni++)
                b[ni] = *reinterpret_cast<const s16x8*>(&Bs[wn + ni * 16 + lo][kk + hi * 8]);
#pragma unroll
            for (int mi = 0; mi < 4; mi++)
#pragma unroll
                for (int ni = 0; ni < 4; ni++)
                    acc[mi][ni] = __builtin_amdgcn_mfma_f32_16x16x32_bf16(
                        a[mi], b[ni], acc[mi][ni], 0, 0, 0);
        }
        __syncthreads();
    }
}

// ---------------- fused QKV projection: z selects {q,k,v} ----------------
// q: out = (acc+bias)*0.125 (softmax scale folded in), normal [MT][DM] bf16
// k: out = acc+bias, normal layout
// v: out = acc+bias written head-transposed: vt[(b*1024 + n)*SQ + l]
__global__ __launch_bounds__(256, 3) void gemm_qkv(
    const unsigned short* __restrict__ Qb, const unsigned short* __restrict__ Kb,
    const unsigned short* __restrict__ Vb,
    const unsigned short* __restrict__ Wq, const unsigned short* __restrict__ Wk,
    const unsigned short* __restrict__ Wv,
    const float* __restrict__ bq, const float* __restrict__ bk, const float* __restrict__ bv,
    unsigned short* __restrict__ qp, unsigned short* __restrict__ kp,
    unsigned short* __restrict__ vt) {
    __shared__ __align__(16) unsigned short As[128][64];
    __shared__ __align__(16) unsigned short Bs[128][64];
    const int t = threadIdx.x;
    const int z = blockIdx.z;
    const unsigned short* A    = (z == 0) ? Qb : (z == 1) ? Kb : Vb;
    const unsigned short* Bm   = (z == 0) ? Wq : (z == 1) ? Wk : Wv;
    const float*          bias = (z == 0) ? bq : (z == 1) ? bk : bv;
    const int m0 = blockIdx.y * 128, n0 = blockIdx.x * 128;

    f32x4 acc[4][4] = {};
    gemm_core(A, Bm, m0, n0, t, As, Bs, acc);

    const int lane = t & 63, w = t >> 6;
    const int wm = (w >> 1) * 64, wn = (w & 1) * 64;
    const int lo = lane & 15, hi = lane >> 4;

    if (z < 2) {
        unsigned short* C = z ? kp : qp;
        const float scale = z ? 1.0f : 0.125f;
#pragma unroll
        for (int mi = 0; mi < 4; mi++)
#pragma unroll
            for (int ni = 0; ni < 4; ni++) {
                int cc = n0 + wn + ni * 16 + lo;
                float bb = bias[cc];
#pragma unroll
                for (int j = 0; j < 4; j++) {
                    int rr = m0 + wm + mi * 16 + hi * 4 + j;
                    C[(size_t)rr * DM + cc] = f2bf((acc[mi][ni][j] + bb) * scale);
                }
            }
    } else {
#pragma unroll
        for (int mi = 0; mi < 4; mi++)
#pragma unroll
            for (int ni = 0; ni < 4; ni++) {
                int cc = n0 + wn + ni * 16 + lo;  // 0..1023 = head*64 + d
                float bb = bias[cc];
#pragma unroll
                for (int j = 0; j < 4; j++) {
                    int rr = m0 + wm + mi * 16 + hi * 4 + j;  // 0..4095 = b*2048 + l
                    size_t idx = ((size_t)(rr >> 11) * DM + cc) * SQ + (rr & (SQ - 1));
                    vt[idx] = f2bf(acc[mi][ni][j] + bb);
                }
            }
    }
}

// ---------------- final projection: fp32 out + bias ----------------
__global__ __launch_bounds__(256, 3) void gemm_out(
    const unsigned short* __restrict__ Ao, const unsigned short* __restrict__ Wo,
    const float* __restrict__ bo, float* __restrict__ Cout) {
    __shared__ __align__(16) unsigned short As[128][64];
    __shared__ __align__(16) unsigned short Bs[128][64];
    const int t = threadIdx.x;
    const int m0 = blockIdx.y * 128, n0 = blockIdx.x * 128;

    f32x4 acc[4][4] = {};
    gemm_core(Ao, Wo, m0, n0, t, As, Bs, acc);

    const int lane = t & 63, w = t >> 6;
    const int wm = (w >> 1) * 64, wn = (w & 1) * 64;
    const int lo = lane & 15, hi = lane >> 4;
#pragma unroll
    for (int mi = 0; mi < 4; mi++)
#pragma unroll
        for (int ni = 0; ni < 4; ni++) {
            int cc = n0 + wn + ni * 16 + lo;
            float bb = bo[cc];
#pragma unroll
            for (int j = 0; j < 4; j++) {
                int rr = m0 + wm + mi * 16 + hi * 4 + j;
                Cout[(size_t)rr * DM + cc] = acc[mi][ni][j] + bb;
            }
        }
}

// ---------------- flash attention ----------------
// grid = (SQ/128, NB*NH); block = 256 (4 waves x 32 q-rows).
// qp,kp: [MT][DM] bf16 (q pre-scaled by 1/8); vt: [NB*DM][SQ] bf16 head-transposed.
// K/V tiles of 128 staged in LDS; online softmax in fp32; P via per-wave LDS.
__global__ __launch_bounds__(256, 2) void attn_k(
    const unsigned short* __restrict__ qp, const unsigned short* __restrict__ kp,
    const unsigned short* __restrict__ vt, unsigned short* __restrict__ ao) {
    __shared__ __align__(16) unsigned short Qs[128][64];
    __shared__ __align__(16) unsigned short Ks[128][64];
    __shared__ __align__(16) unsigned short Vs[64][128];
    __shared__ __align__(16) unsigned short Ps[4][32][128];

    const int t = threadIdx.x;
    const int lane = t & 63, w = t >> 6;
    const int lo = lane & 15, hi = lane >> 4;
    const int q0 = blockIdx.x * 128;
    const int bh = blockIdx.y;         // b*16 + h
    const int b = bh >> 4, h = bh & 15;

    // stage Q once (128 x 64)
#pragma unroll
    for (int i = 0; i < 4; i++) {
        int c = i * 256 + t;
        int r = c >> 3, col = (c & 7) * 8;
        gload16(qp + (size_t)(b * SQ + q0 + r) * DM + h * DH + col, &Qs[r][col]);
    }

    float mrow[2][4], lrow[2][4];
#pragma unroll
    for (int mi = 0; mi < 2; mi++)
#pragma unroll
        for (int j = 0; j < 4; j++) { mrow[mi][j] = -1e30f; lrow[mi][j] = 0.0f; }
    f32x4 oacc[2][4] = {};

    for (int kt = 0; kt < SQ; kt += 128) {
        // stage K tile (128x64) and V tile (64x128, already transposed in global)
#pragma unroll
        for (int i = 0; i < 4; i++) {
            int c = i * 256 + t;
            int r = c >> 3, col = (c & 7) * 8;
            gload16(kp + (size_t)(b * SQ + kt + r) * DM + h * DH + col, &Ks[r][col]);
        }
#pragma unroll
        for (int i = 0; i < 4; i++) {
            int c = i * 256 + t;
            int r = c >> 4, col = (c & 15) * 8;
            gload16(vt + (size_t)(bh * DH + r) * SQ + kt + col, &Vs[r][col]);
        }
        asm volatile("s_waitcnt vmcnt(0)" ::: "memory");
        __syncthreads();

        // S = Q K^T for this wave's 32 rows x 128 cols (q pre-scaled)
        f32x4 sacc[2][8] = {};
#pragma unroll
        for (int kk = 0; kk < 64; kk += 32) {
            s16x8 aq[2];
#pragma unroll
            for (int mi = 0; mi < 2; mi++)
                aq[mi] = *reinterpret_cast<const s16x8*>(&Qs[w * 32 + mi * 16 + lo][kk + hi * 8]);
#pragma unroll
            for (int cf = 0; cf < 8; cf++) {
                s16x8 bk = *reinterpret_cast<const s16x8*>(&Ks[cf * 16 + lo][kk + hi * 8]);
#pragma unroll
                for (int mi = 0; mi < 2; mi++)
                    sacc[mi][cf] = __builtin_amdgcn_mfma_f32_16x16x32_bf16(
                        aq[mi], bk, sacc[mi][cf], 0, 0, 0);
            }
        }

        // online softmax; row r of S lives in lanes with same (lane>>4) group, col = lane&15
#pragma unroll
        for (int mi = 0; mi < 2; mi++) {
#pragma unroll
            for (int j = 0; j < 4; j++) {
                float mx = sacc[mi][0][j];
#pragma unroll
                for (int cf = 1; cf < 8; cf++) mx = fmaxf(mx, sacc[mi][cf][j]);
#pragma unroll
                for (int d = 1; d < 16; d <<= 1) mx = fmaxf(mx, __shfl_xor(mx, d));
                float mold = mrow[mi][j];
                float mnew = fmaxf(mold, mx);
                float fs = __expf(mold - mnew);
                mrow[mi][j] = mnew;
                float psum = 0.0f;
#pragma unroll
                for (int cf = 0; cf < 8; cf++) {
                    float p = __expf(sacc[mi][cf][j] - mnew);
                    psum += p;
                    Ps[w][mi * 16 + hi * 4 + j][cf * 16 + lo] = f2bf(p);
                }
#pragma unroll
                for (int d = 1; d < 16; d <<= 1) psum += __shfl_xor(psum, d);
                lrow[mi][j] = lrow[mi][j] * fs + psum;
#pragma unroll
                for (int ni = 0; ni < 4; ni++) oacc[mi][ni][j] *= fs;
            }
        }

        // PV: out(32x64) += P(32x128) * V(128x64); same-wave LDS RAW is in-order
#pragma unroll
        for (int kc = 0; kc < 4; kc++) {
            s16x8 pa[2];
#pragma unroll
            for (int mi = 0; mi < 2; mi++)
                pa[mi] = *reinterpret_cast<const s16x8*>(&Ps[w][mi * 16 + lo][kc * 32 + hi * 8]);
#pragma unroll
            for (int ni = 0; ni < 4; ni++) {
                s16x8 bvf = *reinterpret_cast<const s16x8*>(&Vs[ni * 16 + lo][kc * 32 + hi * 8]);
#pragma unroll
                for (int mi = 0; mi < 2; mi++)
                    oacc[mi][ni] = __builtin_amdgcn_mfma_f32_16x16x32_bf16(
                        pa[mi], bvf, oacc[mi][ni], 0, 0, 0);
            }
        }
        __syncthreads();
    }

    // epilogue: normalize and store bf16
#pragma unroll
    for (int mi = 0; mi < 2; mi++)
#pragma unroll
        for (int j = 0; j < 4; j++) {
            float inv = 1.0f / lrow[mi][j];
            int rr = q0 + w * 32 + mi * 16 + hi * 4 + j;
#pragma unroll
            for (int ni = 0; ni < 4; ni++) {
                int cc = ni * 16 + lo;
                ao[(size_t)(b * SQ + rr) * DM + h * DH + cc] = f2bf(oacc[mi][ni][j] * inv);
            }
        }
}

extern "C" void kernel_launch(void* const* d_in, const int* in_sizes, int n_in,
                              void* d_out, int out_size, void* d_ws, size_t ws_size,
                              hipStream_t stream) {
    const float* Q  = (const float*)d_in[0];
    const float* K  = (const float*)d_in[1];
    const float* V  = (const float*)d_in[2];
    const float* Wq = (const float*)d_in[3];
    const float* bq = (const float*)d_in[4];
    const float* Wk = (const float*)d_in[5];
    const float* bk = (const float*)d_in[6];
    const float* Wv = (const float*)d_in[7];
    const float* bv = (const float*)d_in[8];
    const float* Wo = (const float*)d_in[9];
    const float* bo = (const float*)d_in[10];

    // workspace layout (all 256B-aligned); total = 64 MiB
    char* ws = (char*)d_ws;
    size_t off = 0;
    auto alloc = [&](size_t bytes) {
        void* p = ws + off;
        off += (bytes + 255) & ~(size_t)255;
        return p;
    };
    const size_t XB = (size_t)MT * DM * 2;  // 8 MiB (bf16 activation)
    const size_t WB = (size_t)DM * DM * 2;  // 2 MiB (bf16 weight)
    unsigned short* qb  = (unsigned short*)alloc(XB);
    unsigned short* kb  = (unsigned short*)alloc(XB);
    unsigned short* vb  = (unsigned short*)alloc(XB);
    unsigned short* wqb = (unsigned short*)alloc(WB);
    unsigned short* wkb = (unsigned short*)alloc(WB);
    unsigned short* wvb = (unsigned short*)alloc(WB);
    unsigned short* wob = (unsigned short*)alloc(WB);
    unsigned short* qp  = (unsigned short*)alloc(XB);
    unsigned short* kp  = (unsigned short*)alloc(XB);
    unsigned short* vtp = (unsigned short*)alloc(XB);
    unsigned short* ao  = (unsigned short*)alloc(XB);

    // 1) casts fp32 -> bf16
    castk<<<dim3(MT * DM / 1024), 256, 0, stream>>>(Q, qb, MT * DM);
    castk<<<dim3(MT * DM / 1024), 256, 0, stream>>>(K, kb, MT * DM);
    castk<<<dim3(MT * DM / 1024), 256, 0, stream>>>(V, vb, MT * DM);
    castk<<<dim3(DM * DM / 1024), 256, 0, stream>>>(Wq, wqb, DM * DM);
    castk<<<dim3(DM * DM / 1024), 256, 0, stream>>>(Wk, wkb, DM * DM);
    castk<<<dim3(DM * DM / 1024), 256, 0, stream>>>(Wv, wvb, DM * DM);
    castk<<<dim3(DM * DM / 1024), 256, 0, stream>>>(Wo, wob, DM * DM);

    // 2) fused QKV projections (z = 0/1/2 -> q/k/v)
    gemm_qkv<<<dim3(DM / 128, MT / 128, 3), 256, 0, stream>>>(
        qb, kb, vb, wqb, wkb, wvb, bq, bk, bv, qp, kp, vtp);

    // 3) flash attention
    attn_k<<<dim3(SQ / 128, NB * NH), 256, 0, stream>>>(qp, kp, vtp, ao);

    // 4) output projection (fp32 out)
    gemm_out<<<dim3(DM / 128, MT / 128), 256, 0, stream>>>(ao, wob, bo, (float*)d_out);
}

// Round 5
// 279.837 us; speedup vs baseline: 1.1442x; 1.1442x over previous
//
#include <hip/hip_runtime.h>
#include <cstdint>
#include <cstddef>

// Problem constants
#define DM 1024   // d_model
#define NH 16     // heads
#define DH 64     // d_head
#define NB 2      // batch
#define SQ 2048   // seq len
#define MT (NB*SQ) // 4096 total rows

typedef float  f32x4 __attribute__((ext_vector_type(4)));
typedef short  s16x8 __attribute__((ext_vector_type(8)));
typedef short  s16x4 __attribute__((ext_vector_type(4)));

// fp32 -> bf16 bits, round-to-nearest-even (no __hip_bfloat16 dependency)
__device__ __forceinline__ unsigned short f2bf(float x) {
    unsigned int u = __float_as_uint(x);
    unsigned int lsb = (u >> 16) & 1u;
    u += 0x7fffu + lsb;
    return (unsigned short)(u >> 16);
}

// async global->LDS, 16 bytes per lane. LDS dest must be wave-uniform base + lane*16,
// which our chunk layouts guarantee (chunk index c = i*256 + tid, LDS offset = c*16).
__device__ __forceinline__ void gload16(const void* g, void* l) {
    __builtin_amdgcn_global_load_lds(
        (const __attribute__((address_space(1))) void*)g,
        (__attribute__((address_space(3))) void*)l,
        16, 0, 0);
}

// ---------------- cast kernel: fp32 -> bf16 (4 elems/thread) ----------------
__global__ __launch_bounds__(256) void castk(const float* __restrict__ in,
                                             unsigned short* __restrict__ out, int n) {
    int i = (blockIdx.x * 256 + threadIdx.x) * 4;
    if (i >= n) return;
    float4 a = *reinterpret_cast<const float4*>(in + i);
    s16x4 r;
    r[0] = (short)f2bf(a.x);
    r[1] = (short)f2bf(a.y);
    r[2] = (short)f2bf(a.z);
    r[3] = (short)f2bf(a.w);
    *reinterpret_cast<s16x4*>(out + i) = r;
}

// ---------------- GEMM core: C[m,n] = sum_k A[m,k]*B[n,k], 128x128 tile, BK=64 ----------------
// m97-style: global_load_lds width 16, single LDS buffer, 2 barriers/K-step,
// 4 waves in 2x2, each 64x64 = 4x4 fragments of 16x16x32 bf16 MFMA.
__device__ __forceinline__ void gemm_core(const unsigned short* __restrict__ A,
                                          const unsigned short* __restrict__ Bm,
                                          int m0, int n0, int t,
                                          unsigned short (*As)[64],
                                          unsigned short (*Bs)[64],
                                          f32x4 acc[4][4]) {
    const int lane = t & 63, w = t >> 6;
    const int wm = (w >> 1) * 64, wn = (w & 1) * 64;
    const int lo = lane & 15, hi = lane >> 4;

    for (int k0 = 0; k0 < DM; k0 += 64) {
        // stage A-tile (128x64) and B-tile (128x64): 1024 chunks of 16B each
#pragma unroll
        for (int i = 0; i < 4; i++) {
            int c = i * 256 + t;
            int r = c >> 3, col = (c & 7) * 8;
            gload16(A  + (size_t)(m0 + r) * DM + k0 + col, &As[r][col]);
            gload16(Bm + (size_t)(n0 + r) * DM + k0 + col, &Bs[r][col]);
        }
        asm volatile("s_waitcnt vmcnt(0)" ::: "memory");
        __syncthreads();

#pragma unroll
        for (int kk = 0; kk < 64; kk += 32) {
            s16x8 a[4], b[4];
#pragma unroll
            for (int mi = 0; mi < 4; mi++)
                a[mi] = *reinterpret_cast<const s16x8*>(&As[wm + mi * 16 + lo][kk + hi * 8]);
#pragma unroll
            for (int ni = 0; ni < 4; ni++)
                b[ni] = *reinterpret_cast<const s16x8*>(&Bs[wn + ni * 16 + lo][kk + hi * 8]);
#pragma unroll
            for (int mi = 0; mi < 4; mi++)
#pragma unroll
                for (int ni = 0; ni < 4; ni++)
                    acc[mi][ni] = __builtin_amdgcn_mfma_f32_16x16x32_bf16(
                        a[mi], b[ni], acc[mi][ni], 0, 0, 0);
        }
        __syncthreads();
    }
}

// ---------------- fused QKV projection: z selects {q,k,v} ----------------
// q: out = (acc+bias)*0.125 (softmax scale folded in), normal [MT][DM] bf16
// k: out = acc+bias, normal layout
// v: out = acc+bias written head-transposed: vt[(b*1024 + n)*SQ + l]
__global__ __launch_bounds__(256, 3) void gemm_qkv(
    const unsigned short* __restrict__ Qb, const unsigned short* __restrict__ Kb,
    const unsigned short* __restrict__ Vb,
    const unsigned short* __restrict__ Wq, const unsigned short* __restrict__ Wk,
    const unsigned short* __restrict__ Wv,
    const float* __restrict__ bq, const float* __restrict__ bk, const float* __restrict__ bv,
    unsigned short* __restrict__ qp, unsigned short* __restrict__ kp,
    unsigned short* __restrict__ vt) {
    __shared__ __align__(16) unsigned short As[128][64];
    __shared__ __align__(16) unsigned short Bs[128][64];
    const int t = threadIdx.x;
    const int z = blockIdx.z;
    const unsigned short* A    = (z == 0) ? Qb : (z == 1) ? Kb : Vb;
    const unsigned short* Bm   = (z == 0) ? Wq : (z == 1) ? Wk : Wv;
    const float*          bias = (z == 0) ? bq : (z == 1) ? bk : bv;
    const int m0 = blockIdx.y * 128, n0 = blockIdx.x * 128;

    f32x4 acc[4][4] = {};
    gemm_core(A, Bm, m0, n0, t, As, Bs, acc);

    const int lane = t & 63, w = t >> 6;
    const int wm = (w >> 1) * 64, wn = (w & 1) * 64;
    const int lo = lane & 15, hi = lane >> 4;

    if (z < 2) {
        unsigned short* C = z ? kp : qp;
        const float scale = z ? 1.0f : 0.125f;
#pragma unroll
        for (int mi = 0; mi < 4; mi++)
#pragma unroll
            for (int ni = 0; ni < 4; ni++) {
                int cc = n0 + wn + ni * 16 + lo;
                float bb = bias[cc];
#pragma unroll
                for (int j = 0; j < 4; j++) {
                    int rr = m0 + wm + mi * 16 + hi * 4 + j;
                    C[(size_t)rr * DM + cc] = f2bf((acc[mi][ni][j] + bb) * scale);
                }
            }
    } else {
#pragma unroll
        for (int mi = 0; mi < 4; mi++)
#pragma unroll
            for (int ni = 0; ni < 4; ni++) {
                int cc = n0 + wn + ni * 16 + lo;  // 0..1023 = head*64 + d
                float bb = bias[cc];
#pragma unroll
                for (int j = 0; j < 4; j++) {
                    int rr = m0 + wm + mi * 16 + hi * 4 + j;  // 0..4095 = b*2048 + l
                    size_t idx = ((size_t)(rr >> 11) * DM + cc) * SQ + (rr & (SQ - 1));
                    vt[idx] = f2bf(acc[mi][ni][j] + bb);
                }
            }
    }
}

// ---------------- final projection: fp32 out + bias ----------------
__global__ __launch_bounds__(256, 3) void gemm_out(
    const unsigned short* __restrict__ Ao, const unsigned short* __restrict__ Wo,
    const float* __restrict__ bo, float* __restrict__ Cout) {
    __shared__ __align__(16) unsigned short As[128][64];
    __shared__ __align__(16) unsigned short Bs[128][64];
    const int t = threadIdx.x;
    const int m0 = blockIdx.y * 128, n0 = blockIdx.x * 128;

    f32x4 acc[4][4] = {};
    gemm_core(Ao, Wo, m0, n0, t, As, Bs, acc);

    const int lane = t & 63, w = t >> 6;
    const int wm = (w >> 1) * 64, wn = (w & 1) * 64;
    const int lo = lane & 15, hi = lane >> 4;
#pragma unroll
    for (int mi = 0; mi < 4; mi++)
#pragma unroll
        for (int ni = 0; ni < 4; ni++) {
            int cc = n0 + wn + ni * 16 + lo;
            float bb = bo[cc];
#pragma unroll
            for (int j = 0; j < 4; j++) {
                int rr = m0 + wm + mi * 16 + hi * 4 + j;
                Cout[(size_t)rr * DM + cc] = acc[mi][ni][j] + bb;
            }
        }
}

// ---------------- flash attention (XOR-swizzled LDS) ----------------
// grid = (SQ/128, NB*NH); block = 256 (4 waves x 32 q-rows).
// qp,kp: [MT][DM] bf16 (q pre-scaled by 1/8); vt: [NB*DM][SQ] bf16 head-transposed.
//
// Bank-conflict fix (T2, rule #21): every LDS buffer here has a power-of-2 row
// stride (128B or 256B), and every ds_read_b128 has 16 lanes reading different
// rows at the same 16B slot -> same bank group -> 16-way conflict (measured
// 3.4e7 SQ_LDS_BANK_CONFLICT ~= 40% of all cycles). Fix: XOR the 16B-slot index
// with (row & (nslots-1)). gload_lds writes LDS linearly, so the *global source*
// column is inverse-swizzled at stage time; reads apply the same XOR. Ps is
// VALU-written, so write and read both apply the XOR directly.
__global__ __launch_bounds__(256, 2) void attn_k(
    const unsigned short* __restrict__ qp, const unsigned short* __restrict__ kp,
    const unsigned short* __restrict__ vt, unsigned short* __restrict__ ao) {
    __shared__ __align__(16) unsigned short Qs[128][64];   // 8 slots/row, swz mask row&7
    __shared__ __align__(16) unsigned short Ks[128][64];   // 8 slots/row, swz mask row&7
    __shared__ __align__(16) unsigned short Vs[64][128];   // 16 slots/row, swz mask row&15
    __shared__ __align__(16) unsigned short Ps[4][32][128];// 16 slots/row, swz mask row&15

    const int t = threadIdx.x;
    const int lane = t & 63, w = t >> 6;
    const int lo = lane & 15, hi = lane >> 4;
    const int q0 = blockIdx.x * 128;
    const int bh = blockIdx.y;         // b*16 + h
    const int b = bh >> 4, h = bh & 15;

    // stage Q once (128 x 64), source column inverse-swizzled
#pragma unroll
    for (int i = 0; i < 4; i++) {
        int c = i * 256 + t;
        int r = c >> 3, col = ((c & 7) ^ (r & 7)) * 8;
        gload16(qp + (size_t)(b * SQ + q0 + r) * DM + h * DH + col, &Qs[r][(c & 7) * 8]);
    }

    float mrow[2][4], lrow[2][4];
#pragma unroll
    for (int mi = 0; mi < 2; mi++)
#pragma unroll
        for (int j = 0; j < 4; j++) { mrow[mi][j] = -1e30f; lrow[mi][j] = 0.0f; }
    f32x4 oacc[2][4] = {};

    for (int kt = 0; kt < SQ; kt += 128) {
        // stage K tile (128x64) and V tile (64x128), source columns inverse-swizzled
#pragma unroll
        for (int i = 0; i < 4; i++) {
            int c = i * 256 + t;
            int r = c >> 3, col = ((c & 7) ^ (r & 7)) * 8;
            gload16(kp + (size_t)(b * SQ + kt + r) * DM + h * DH + col, &Ks[r][(c & 7) * 8]);
        }
#pragma unroll
        for (int i = 0; i < 4; i++) {
            int c = i * 256 + t;
            int r = c >> 4, col = ((c & 15) ^ (r & 15)) * 8;
            gload16(vt + (size_t)(bh * DH + r) * SQ + kt + col, &Vs[r][(c & 15) * 8]);
        }
        asm volatile("s_waitcnt vmcnt(0)" ::: "memory");
        __syncthreads();

        // S = Q K^T for this wave's 32 rows x 128 cols (q pre-scaled)
        f32x4 sacc[2][8] = {};
#pragma unroll
        for (int kk = 0; kk < 64; kk += 32) {
            s16x8 aq[2];
#pragma unroll
            for (int mi = 0; mi < 2; mi++) {
                int qr = w * 32 + mi * 16 + lo;
                aq[mi] = *reinterpret_cast<const s16x8*>(
                    &Qs[qr][((kk / 8 + hi) ^ (qr & 7)) * 8]);
            }
#pragma unroll
            for (int cf = 0; cf < 8; cf++) {
                int kr = cf * 16 + lo;
                s16x8 bk = *reinterpret_cast<const s16x8*>(
                    &Ks[kr][((kk / 8 + hi) ^ (kr & 7)) * 8]);
#pragma unroll
                for (int mi = 0; mi < 2; mi++)
                    sacc[mi][cf] = __builtin_amdgcn_mfma_f32_16x16x32_bf16(
                        aq[mi], bk, sacc[mi][cf], 0, 0, 0);
            }
        }

        // online softmax; S row (q) = mi*16 + hi*4 + j, col (k) = cf*16 + lo
#pragma unroll
        for (int mi = 0; mi < 2; mi++) {
#pragma unroll
            for (int j = 0; j < 4; j++) {
                float mx = sacc[mi][0][j];
#pragma unroll
                for (int cf = 1; cf < 8; cf++) mx = fmaxf(mx, sacc[mi][cf][j]);
#pragma unroll
                for (int d = 1; d < 16; d <<= 1) mx = fmaxf(mx, __shfl_xor(mx, d));
                float mold = mrow[mi][j];
                float mnew = fmaxf(mold, mx);
                float fs = __expf(mold - mnew);
                mrow[mi][j] = mnew;
                float psum = 0.0f;
                int prow = mi * 16 + hi * 4 + j;
                int pm = prow & 15;
#pragma unroll
                for (int cf = 0; cf < 8; cf++) {
                    float p = __expf(sacc[mi][cf][j] - mnew);
                    psum += p;
                    // P[prow][cf*16+lo]: slot = cf*2 + (lo>>3), swizzle ^ (prow&15)
                    Ps[w][prow][(((cf * 2 + (lo >> 3)) ^ pm) * 8) + (lo & 7)] = f2bf(p);
                }
#pragma unroll
                for (int d = 1; d < 16; d <<= 1) psum += __shfl_xor(psum, d);
                lrow[mi][j] = lrow[mi][j] * fs + psum;
#pragma unroll
                for (int ni = 0; ni < 4; ni++) oacc[mi][ni][j] *= fs;
            }
        }

        // PV: out(32x64) += P(32x128) * V(128x64); same-wave LDS RAW is in-order
#pragma unroll
        for (int kc = 0; kc < 4; kc++) {
            s16x8 pa[2];
#pragma unroll
            for (int mi = 0; mi < 2; mi++) {
                int pr = mi * 16 + lo;  // pr & 15 == lo
                pa[mi] = *reinterpret_cast<const s16x8*>(
                    &Ps[w][pr][((kc * 4 + hi) ^ (pr & 15)) * 8]);
            }
#pragma unroll
            for (int ni = 0; ni < 4; ni++) {
                int vr = ni * 16 + lo;  // vr & 15 == lo
                s16x8 bvf = *reinterpret_cast<const s16x8*>(
                    &Vs[vr][((kc * 4 + hi) ^ (vr & 15)) * 8]);
#pragma unroll
                for (int mi = 0; mi < 2; mi++)
                    oacc[mi][ni] = __builtin_amdgcn_mfma_f32_16x16x32_bf16(
                        pa[mi], bvf, oacc[mi][ni], 0, 0, 0);
            }
        }
        __syncthreads();
    }

    // epilogue: normalize and store bf16
#pragma unroll
    for (int mi = 0; mi < 2; mi++)
#pragma unroll
        for (int j = 0; j < 4; j++) {
            float inv = 1.0f / lrow[mi][j];
            int rr = q0 + w * 32 + mi * 16 + hi * 4 + j;
#pragma unroll
            for (int ni = 0; ni < 4; ni++) {
                int cc = ni * 16 + lo;
                ao[(size_t)(b * SQ + rr) * DM + h * DH + cc] = f2bf(oacc[mi][ni][j] * inv);
            }
        }
}

extern "C" void kernel_launch(void* const* d_in, const int* in_sizes, int n_in,
                              void* d_out, int out_size, void* d_ws, size_t ws_size,
                              hipStream_t stream) {
    const float* Q  = (const float*)d_in[0];
    const float* K  = (const float*)d_in[1];
    const float* V  = (const float*)d_in[2];
    const float* Wq = (const float*)d_in[3];
    const float* bq = (const float*)d_in[4];
    const float* Wk = (const float*)d_in[5];
    const float* bk = (const float*)d_in[6];
    const float* Wv = (const float*)d_in[7];
    const float* bv = (const float*)d_in[8];
    const float* Wo = (const float*)d_in[9];
    const float* bo = (const float*)d_in[10];

    // workspace layout (all 256B-aligned); total = 64 MiB
    char* ws = (char*)d_ws;
    size_t off = 0;
    auto alloc = [&](size_t bytes) {
        void* p = ws + off;
        off += (bytes + 255) & ~(size_t)255;
        return p;
    };
    const size_t XB = (size_t)MT * DM * 2;  // 8 MiB (bf16 activation)
    const size_t WB = (size_t)DM * DM * 2;  // 2 MiB (bf16 weight)
    unsigned short* qb  = (unsigned short*)alloc(XB);
    unsigned short* kb  = (unsigned short*)alloc(XB);
    unsigned short* vb  = (unsigned short*)alloc(XB);
    unsigned short* wqb = (unsigned short*)alloc(WB);
    unsigned short* wkb = (unsigned short*)alloc(WB);
    unsigned short* wvb = (unsigned short*)alloc(WB);
    unsigned short* wob = (unsigned short*)alloc(WB);
    unsigned short* qp  = (unsigned short*)alloc(XB);
    unsigned short* kp  = (unsigned short*)alloc(XB);
    unsigned short* vtp = (unsigned short*)alloc(XB);
    unsigned short* ao  = (unsigned short*)alloc(XB);

    // 1) casts fp32 -> bf16
    castk<<<dim3(MT * DM / 1024), 256, 0, stream>>>(Q, qb, MT * DM);
    castk<<<dim3(MT * DM / 1024), 256, 0, stream>>>(K, kb, MT * DM);
    castk<<<dim3(MT * DM / 1024), 256, 0, stream>>>(V, vb, MT * DM);
    castk<<<dim3(DM * DM / 1024), 256, 0, stream>>>(Wq, wqb, DM * DM);
    castk<<<dim3(DM * DM / 1024), 256, 0, stream>>>(Wk, wkb, DM * DM);
    castk<<<dim3(DM * DM / 1024), 256, 0, stream>>>(Wv, wvb, DM * DM);
    castk<<<dim3(DM * DM / 1024), 256, 0, stream>>>(Wo, wob, DM * DM);

    // 2) fused QKV projections (z = 0/1/2 -> q/k/v)
    gemm_qkv<<<dim3(DM / 128, MT / 128, 3), 256, 0, stream>>>(
        qb, kb, vb, wqb, wkb, wvb, bq, bk, bv, qp, kp, vtp);

    // 3) flash attention
    attn_k<<<dim3(SQ / 128, NB * NH), 256, 0, stream>>>(qp, kp, vtp, ao);

    // 4) output projection (fp32 out)
    gemm_out<<<dim3(DM / 128, MT / 128), 256, 0, stream>>>(ao, wob, bo, (float*)d_out);
}

// Round 6
// 269.204 us; speedup vs baseline: 1.1894x; 1.0395x over previous
//
#include <hip/hip_runtime.h>
#include <cstdint>
#include <cstddef>

// Problem constants
#define DM 1024   // d_model
#define NH 16     // heads
#define DH 64     // d_head
#define NB 2      // batch
#define SQ 2048   // seq len
#define MT (NB*SQ) // 4096 total rows

typedef float  f32x4  __attribute__((ext_vector_type(4)));
typedef float  f32x16 __attribute__((ext_vector_type(16)));
typedef short  s16x8 __attribute__((ext_vector_type(8)));
typedef short  s16x4 __attribute__((ext_vector_type(4)));

// fp32 -> bf16 bits, round-to-nearest-even (no __hip_bfloat16 dependency)
__device__ __forceinline__ unsigned short f2bf(float x) {
    unsigned int u = __float_as_uint(x);
    unsigned int lsb = (u >> 16) & 1u;
    u += 0x7fffu + lsb;
    return (unsigned short)(u >> 16);
}

// async global->LDS, 16 bytes per lane. LDS dest must be wave-uniform base + lane*16,
// which our chunk layouts guarantee (chunk index c = i*256 + tid, LDS offset = c*16).
__device__ __forceinline__ void gload16(const void* g, void* l) {
    __builtin_amdgcn_global_load_lds(
        (const __attribute__((address_space(1))) void*)g,
        (__attribute__((address_space(3))) void*)l,
        16, 0, 0);
}

// ---------------- cast kernel: fp32 -> bf16 (4 elems/thread) ----------------
__global__ __launch_bounds__(256) void castk(const float* __restrict__ in,
                                             unsigned short* __restrict__ out, int n) {
    int i = (blockIdx.x * 256 + threadIdx.x) * 4;
    if (i >= n) return;
    float4 a = *reinterpret_cast<const float4*>(in + i);
    s16x4 r;
    r[0] = (short)f2bf(a.x);
    r[1] = (short)f2bf(a.y);
    r[2] = (short)f2bf(a.z);
    r[3] = (short)f2bf(a.w);
    *reinterpret_cast<s16x4*>(out + i) = r;
}

// ---------------- GEMM core: C[m,n] = sum_k A[m,k]*B[n,k], 128x128 tile, BK=64 ----------------
__device__ __forceinline__ void gemm_core(const unsigned short* __restrict__ A,
                                          const unsigned short* __restrict__ Bm,
                                          int m0, int n0, int t,
                                          unsigned short (*As)[64],
                                          unsigned short (*Bs)[64],
                                          f32x4 acc[4][4]) {
    const int lane = t & 63, w = t >> 6;
    const int wm = (w >> 1) * 64, wn = (w & 1) * 64;
    const int lo = lane & 15, hi = lane >> 4;

    for (int k0 = 0; k0 < DM; k0 += 64) {
#pragma unroll
        for (int i = 0; i < 4; i++) {
            int c = i * 256 + t;
            int r = c >> 3, col = (c & 7) * 8;
            gload16(A  + (size_t)(m0 + r) * DM + k0 + col, &As[r][col]);
            gload16(Bm + (size_t)(n0 + r) * DM + k0 + col, &Bs[r][col]);
        }
        asm volatile("s_waitcnt vmcnt(0)" ::: "memory");
        __syncthreads();

#pragma unroll
        for (int kk = 0; kk < 64; kk += 32) {
            s16x8 a[4], b[4];
#pragma unroll
            for (int mi = 0; mi < 4; mi++)
                a[mi] = *reinterpret_cast<const s16x8*>(&As[wm + mi * 16 + lo][kk + hi * 8]);
#pragma unroll
            for (int ni = 0; ni < 4; ni++)
                b[ni] = *reinterpret_cast<const s16x8*>(&Bs[wn + ni * 16 + lo][kk + hi * 8]);
#pragma unroll
            for (int mi = 0; mi < 4; mi++)
#pragma unroll
                for (int ni = 0; ni < 4; ni++)
                    acc[mi][ni] = __builtin_amdgcn_mfma_f32_16x16x32_bf16(
                        a[mi], b[ni], acc[mi][ni], 0, 0, 0);
        }
        __syncthreads();
    }
}

// ---------------- fused QKV projection: z selects {q,k,v} ----------------
// q: out = (acc+bias)*(0.125*log2(e)) -- softmax scale AND exp2-domain fold
// k: out = acc+bias, normal layout
// v: out = acc+bias written head-transposed: vt[(b*1024 + n)*SQ + l]
__global__ __launch_bounds__(256, 3) void gemm_qkv(
    const unsigned short* __restrict__ Qb, const unsigned short* __restrict__ Kb,
    const unsigned short* __restrict__ Vb,
    const unsigned short* __restrict__ Wq, const unsigned short* __restrict__ Wk,
    const unsigned short* __restrict__ Wv,
    const float* __restrict__ bq, const float* __restrict__ bk, const float* __restrict__ bv,
    unsigned short* __restrict__ qp, unsigned short* __restrict__ kp,
    unsigned short* __restrict__ vt) {
    __shared__ __align__(16) unsigned short As[128][64];
    __shared__ __align__(16) unsigned short Bs[128][64];
    const int t = threadIdx.x;
    const int z = blockIdx.z;
    const unsigned short* A    = (z == 0) ? Qb : (z == 1) ? Kb : Vb;
    const unsigned short* Bm   = (z == 0) ? Wq : (z == 1) ? Wk : Wv;
    const float*          bias = (z == 0) ? bq : (z == 1) ? bk : bv;
    const int m0 = blockIdx.y * 128, n0 = blockIdx.x * 128;

    f32x4 acc[4][4] = {};
    gemm_core(A, Bm, m0, n0, t, As, Bs, acc);

    const int lane = t & 63, w = t >> 6;
    const int wm = (w >> 1) * 64, wn = (w & 1) * 64;
    const int lo = lane & 15, hi = lane >> 4;

    if (z < 2) {
        unsigned short* C = z ? kp : qp;
        // q-scale: 1/sqrt(64) * log2(e) so attention scores are in the exp2 domain
        const float scale = z ? 1.0f : 0.18033688011112042f;
#pragma unroll
        for (int mi = 0; mi < 4; mi++)
#pragma unroll
            for (int ni = 0; ni < 4; ni++) {
                int cc = n0 + wn + ni * 16 + lo;
                float bb = bias[cc];
#pragma unroll
                for (int j = 0; j < 4; j++) {
                    int rr = m0 + wm + mi * 16 + hi * 4 + j;
                    C[(size_t)rr * DM + cc] = f2bf((acc[mi][ni][j] + bb) * scale);
                }
            }
    } else {
#pragma unroll
        for (int mi = 0; mi < 4; mi++)
#pragma unroll
            for (int ni = 0; ni < 4; ni++) {
                int cc = n0 + wn + ni * 16 + lo;  // 0..1023 = head*64 + d
                float bb = bias[cc];
#pragma unroll
                for (int j = 0; j < 4; j++) {
                    int rr = m0 + wm + mi * 16 + hi * 4 + j;  // 0..4095 = b*2048 + l
                    size_t idx = ((size_t)(rr >> 11) * DM + cc) * SQ + (rr & (SQ - 1));
                    vt[idx] = f2bf(acc[mi][ni][j] + bb);
                }
            }
    }
}

// ---------------- final projection: fp32 out + bias ----------------
__global__ __launch_bounds__(256, 3) void gemm_out(
    const unsigned short* __restrict__ Ao, const unsigned short* __restrict__ Wo,
    const float* __restrict__ bo, float* __restrict__ Cout) {
    __shared__ __align__(16) unsigned short As[128][64];
    __shared__ __align__(16) unsigned short Bs[128][64];
    const int t = threadIdx.x;
    const int m0 = blockIdx.y * 128, n0 = blockIdx.x * 128;

    f32x4 acc[4][4] = {};
    gemm_core(Ao, Wo, m0, n0, t, As, Bs, acc);

    const int lane = t & 63, w = t >> 6;
    const int wm = (w >> 1) * 64, wn = (w & 1) * 64;
    const int lo = lane & 15, hi = lane >> 4;
#pragma unroll
    for (int mi = 0; mi < 4; mi++)
#pragma unroll
        for (int ni = 0; ni < 4; ni++) {
            int cc = n0 + wn + ni * 16 + lo;
            float bb = bo[cc];
#pragma unroll
            for (int j = 0; j < 4; j++) {
                int rr = m0 + wm + mi * 16 + hi * 4 + j;
                Cout[(size_t)rr * DM + cc] = acc[mi][ni][j] + bb;
            }
        }
}

// ---------------- flash attention: swapped QK^T, 32x32 MFMA, in-register P ----------------
// grid = (SQ/128, NB*NH); block = 256 (4 waves x 32 q-rows each).
// qp: [MT][DM] bf16, pre-scaled by 0.125*log2e (scores land in exp2 domain).
// kp: [MT][DM] bf16. vt: [NB*DM][SQ] bf16 head-transposed (V^T per head).
//
// Per wave: S^T = mfma_32x32x16(K-frag, Q-frag): lane holds 64 scores of ONE
// q-row (q = lane&31; lane^32 holds the other 64 of the same row). Softmax is
// in-lane + one shfl_xor(32) for max and sum. P is packed to bf16 in-register
// and exchanged with lane^32 to build PV's B-operand (no P LDS round-trip).
// PV computes O^T = mfma(V^T-frag, P-frag) so rescale/normalize are lane-local.
// LDS = Qs+Ks+Vs = 48 KB (Ps eliminated). XOR swizzle as before (conflicts==0).
__global__ __launch_bounds__(256, 2) void attn_k(
    const unsigned short* __restrict__ qp, const unsigned short* __restrict__ kp,
    const unsigned short* __restrict__ vt, unsigned short* __restrict__ ao) {
    __shared__ __align__(16) unsigned short Qs[128][64];   // 8 slots/row, swz ^(row&7)
    __shared__ __align__(16) unsigned short Ks[128][64];   // 8 slots/row, swz ^(row&7)
    __shared__ __align__(16) unsigned short Vs[64][128];   // 16 slots/row, swz ^(row&15)

    const int t = threadIdx.x;
    const int lane = t & 63, w = t >> 6;
    const int l5 = lane & 31, hb = lane >> 5;
    const int q0 = blockIdx.x * 128;
    const int bh = blockIdx.y;         // b*16 + h
    const int b = bh >> 4, h = bh & 15;

    // stage Q once (128 x 64), source column inverse-swizzled
#pragma unroll
    for (int i = 0; i < 4; i++) {
        int c = i * 256 + t;
        int r = c >> 3, col = ((c & 7) ^ (r & 7)) * 8;
        gload16(qp + (size_t)(b * SQ + q0 + r) * DM + h * DH + col, &Qs[r][(c & 7) * 8]);
    }

    float mrow = -1e30f, lrow = 0.0f;
    f32x16 oaccT[2] = {};   // O^T frags: d = dblk*32+(reg&3)+8*(reg>>2)+4*hb, q = w*32+l5
    s16x8 qfrag[4];         // Q B-operand frags, loaded once (k-dim kk*16+hb*8+e)

    for (int kt = 0; kt < SQ; kt += 128) {
        // stage K tile (128x64) and V tile (64x128), source columns inverse-swizzled
#pragma unroll
        for (int i = 0; i < 4; i++) {
            int c = i * 256 + t;
            int r = c >> 3, col = ((c & 7) ^ (r & 7)) * 8;
            gload16(kp + (size_t)(b * SQ + kt + r) * DM + h * DH + col, &Ks[r][(c & 7) * 8]);
        }
#pragma unroll
        for (int i = 0; i < 4; i++) {
            int c = i * 256 + t;
            int r = c >> 4, col = ((c & 15) ^ (r & 15)) * 8;
            gload16(vt + (size_t)(bh * DH + r) * SQ + kt + col, &Vs[r][(c & 15) * 8]);
        }
        asm volatile("s_waitcnt vmcnt(0)" ::: "memory");
        __syncthreads();

        if (kt == 0) {
#pragma unroll
            for (int kk = 0; kk < 4; kk++) {
                int qr = w * 32 + l5;
                qfrag[kk] = *reinterpret_cast<const s16x8*>(
                    &Qs[qr][((kk * 2 + hb) ^ (qr & 7)) * 8]);
            }
        }

        // S^T = K . Q^T : sT[ks] holds k-rows ks*32+(reg&3)+8*(reg>>2)+4*hb, q-col l5
        f32x16 sT[4] = {};
#pragma unroll
        for (int ks = 0; ks < 4; ks++) {
#pragma unroll
            for (int kk = 0; kk < 4; kk++) {
                int kr = ks * 32 + l5;
                s16x8 kf = *reinterpret_cast<const s16x8*>(
                    &Ks[kr][((kk * 2 + hb) ^ (kr & 7)) * 8]);
                sT[ks] = __builtin_amdgcn_mfma_f32_32x32x16_bf16(
                    kf, qfrag[kk], sT[ks], 0, 0, 0);
            }
        }

        // in-lane online softmax (exp2 domain); lane^32 holds other half of the row
        float mx = -3.0e38f;
#pragma unroll
        for (int ks = 0; ks < 4; ks++) {
            float a0 = fmaxf(fmaxf(sT[ks][0], sT[ks][1]), fmaxf(sT[ks][2], sT[ks][3]));
            float a1 = fmaxf(fmaxf(sT[ks][4], sT[ks][5]), fmaxf(sT[ks][6], sT[ks][7]));
            float a2 = fmaxf(fmaxf(sT[ks][8], sT[ks][9]), fmaxf(sT[ks][10], sT[ks][11]));
            float a3 = fmaxf(fmaxf(sT[ks][12], sT[ks][13]), fmaxf(sT[ks][14], sT[ks][15]));
            mx = fmaxf(mx, fmaxf(fmaxf(a0, a1), fmaxf(a2, a3)));
        }
        mx = fmaxf(mx, __shfl_xor(mx, 32));
        float mnew = fmaxf(mrow, mx);
        float fs = exp2f(mrow - mnew);
        mrow = mnew;
        float ps = 0.0f;
#pragma unroll
        for (int ks = 0; ks < 4; ks++)
#pragma unroll
            for (int r = 0; r < 16; r++) {
                float e = exp2f(sT[ks][r] - mnew);
                sT[ks][r] = e;
                ps += e;
            }
        ps += __shfl_xor(ps, 32);
        lrow = lrow * fs + ps;
        oaccT[0] *= fs;
        oaccT[1] *= fs;

        // PV: O^T += V^T . P^T, P built in-register (pack bf16 + lane^32 exchange)
#pragma unroll
        for (int ks = 0; ks < 4; ks++) {
            unsigned int pw0[4], pw1[4];   // pw0[m]=pack(j0,j1), pw1[m]=pack(j2,j3)
#pragma unroll
            for (int m = 0; m < 4; m++) {
                pw0[m] = (unsigned int)f2bf(sT[ks][4 * m]) |
                         ((unsigned int)f2bf(sT[ks][4 * m + 1]) << 16);
                pw1[m] = (unsigned int)f2bf(sT[ks][4 * m + 2]) |
                         ((unsigned int)f2bf(sT[ks][4 * m + 3]) << 16);
            }
#pragma unroll
            for (int tt = 0; tt < 2; tt++) {
                // hb=0 lanes send m=2t+1 words (partner hb=1 needs them);
                // hb=1 lanes send m=2t words (partner hb=0 needs them).
                unsigned int s0 = hb ? pw0[2 * tt] : pw0[2 * tt + 1];
                unsigned int s1 = hb ? pw1[2 * tt] : pw1[2 * tt + 1];
                unsigned int r0 = __shfl_xor(s0, 32);
                unsigned int r1 = __shfl_xor(s1, 32);
                union { unsigned int u[4]; s16x8 v; } uu;
                if (hb == 0) { uu.u[0] = pw0[2 * tt]; uu.u[1] = pw1[2 * tt];
                               uu.u[2] = r0;          uu.u[3] = r1; }
                else         { uu.u[0] = r0;          uu.u[1] = r1;
                               uu.u[2] = pw0[2 * tt + 1]; uu.u[3] = pw1[2 * tt + 1]; }
                s16x8 pf = uu.v;
#pragma unroll
                for (int dblk = 0; dblk < 2; dblk++) {
                    int vr = dblk * 32 + l5;
                    int sl = ((ks * 2 + tt) * 2 + hb) ^ (vr & 15);
                    s16x8 vf = *reinterpret_cast<const s16x8*>(&Vs[vr][sl * 8]);
                    oaccT[dblk] = __builtin_amdgcn_mfma_f32_32x32x16_bf16(
                        vf, pf, oaccT[dblk], 0, 0, 0);
                }
            }
        }
        __syncthreads();
    }

    // epilogue: normalize (lane-local q) and store bf16, 8B per store
    float inv = 1.0f / lrow;
    size_t rowbase = (size_t)(b * SQ + q0 + w * 32 + l5) * DM + h * DH;
#pragma unroll
    for (int dblk = 0; dblk < 2; dblk++)
#pragma unroll
        for (int g = 0; g < 4; g++) {
            s16x4 st;
#pragma unroll
            for (int j = 0; j < 4; j++)
                st[j] = (short)f2bf(oaccT[dblk][4 * g + j] * inv);
            *reinterpret_cast<s16x4*>(&ao[rowbase + dblk * 32 + 8 * g + 4 * hb]) = st;
        }
}

extern "C" void kernel_launch(void* const* d_in, const int* in_sizes, int n_in,
                              void* d_out, int out_size, void* d_ws, size_t ws_size,
                              hipStream_t stream) {
    const float* Q  = (const float*)d_in[0];
    const float* K  = (const float*)d_in[1];
    const float* V  = (const float*)d_in[2];
    const float* Wq = (const float*)d_in[3];
    const float* bq = (const float*)d_in[4];
    const float* Wk = (const float*)d_in[5];
    const float* bk = (const float*)d_in[6];
    const float* Wv = (const float*)d_in[7];
    const float* bv = (const float*)d_in[8];
    const float* Wo = (const float*)d_in[9];
    const float* bo = (const float*)d_in[10];

    // workspace layout (all 256B-aligned); total = 64 MiB
    char* ws = (char*)d_ws;
    size_t off = 0;
    auto alloc = [&](size_t bytes) {
        void* p = ws + off;
        off += (bytes + 255) & ~(size_t)255;
        return p;
    };
    const size_t XB = (size_t)MT * DM * 2;  // 8 MiB (bf16 activation)
    const size_t WB = (size_t)DM * DM * 2;  // 2 MiB (bf16 weight)
    unsigned short* qb  = (unsigned short*)alloc(XB);
    unsigned short* kb  = (unsigned short*)alloc(XB);
    unsigned short* vb  = (unsigned short*)alloc(XB);
    unsigned short* wqb = (unsigned short*)alloc(WB);
    unsigned short* wkb = (unsigned short*)alloc(WB);
    unsigned short* wvb = (unsigned short*)alloc(WB);
    unsigned short* wob = (unsigned short*)alloc(WB);
    unsigned short* qp  = (unsigned short*)alloc(XB);
    unsigned short* kp  = (unsigned short*)alloc(XB);
    unsigned short* vtp = (unsigned short*)alloc(XB);
    unsigned short* ao  = (unsigned short*)alloc(XB);

    // 1) casts fp32 -> bf16
    castk<<<dim3(MT * DM / 1024), 256, 0, stream>>>(Q, qb, MT * DM);
    castk<<<dim3(MT * DM / 1024), 256, 0, stream>>>(K, kb, MT * DM);
    castk<<<dim3(MT * DM / 1024), 256, 0, stream>>>(V, vb, MT * DM);
    castk<<<dim3(DM * DM / 1024), 256, 0, stream>>>(Wq, wqb, DM * DM);
    castk<<<dim3(DM * DM / 1024), 256, 0, stream>>>(Wk, wkb, DM * DM);
    castk<<<dim3(DM * DM / 1024), 256, 0, stream>>>(Wv, wvb, DM * DM);
    castk<<<dim3(DM * DM / 1024), 256, 0, stream>>>(Wo, wob, DM * DM);

    // 2) fused QKV projections (z = 0/1/2 -> q/k/v)
    gemm_qkv<<<dim3(DM / 128, MT / 128, 3), 256, 0, stream>>>(
        qb, kb, vb, wqb, wkb, wvb, bq, bk, bv, qp, kp, vtp);

    // 3) flash attention
    attn_k<<<dim3(SQ / 128, NB * NH), 256, 0, stream>>>(qp, kp, vtp, ao);

    // 4) output projection (fp32 out)
    gemm_out<<<dim3(DM / 128, MT / 128), 256, 0, stream>>>(ao, wob, bo, (float*)d_out);
}

// Round 8
// 263.026 us; speedup vs baseline: 1.2173x; 1.0235x over previous
//
#include <hip/hip_runtime.h>
#include <cstdint>
#include <cstddef>

// Problem constants
#define DM 1024   // d_model
#define NH 16     // heads
#define DH 64     // d_head
#define NB 2      // batch
#define SQ 2048   // seq len
#define MT (NB*SQ) // 4096 total rows

typedef float  f32x4  __attribute__((ext_vector_type(4)));
typedef float  f32x16 __attribute__((ext_vector_type(16)));
typedef short  s16x8 __attribute__((ext_vector_type(8)));
typedef short  s16x4 __attribute__((ext_vector_type(4)));

// fp32 -> bf16 bits, round-to-nearest-even (no __hip_bfloat16 dependency)
__device__ __forceinline__ unsigned short f2bf(float x) {
    unsigned int u = __float_as_uint(x);
    unsigned int lsb = (u >> 16) & 1u;
    u += 0x7fffu + lsb;
    return (unsigned short)(u >> 16);
}

// packed fp32->bf16x2 (RNE), dst.lo16 = bf16(lo), dst.hi16 = bf16(hi)
__device__ __forceinline__ unsigned int cvtpk(float lo, float hi) {
    unsigned int r;
    asm("v_cvt_pk_bf16_f32 %0, %1, %2" : "=v"(r) : "v"(lo), "v"(hi));
    return r;
}

// async global->LDS, 16 bytes per lane (dest = wave-uniform base + lane*16)
__device__ __forceinline__ void gload16(const void* g, void* l) {
    __builtin_amdgcn_global_load_lds(
        (const __attribute__((address_space(1))) void*)g,
        (__attribute__((address_space(3))) void*)l,
        16, 0, 0);
}

// ---------------- cast kernel: fp32 -> bf16 (4 elems/thread) ----------------
__global__ __launch_bounds__(256) void castk(const float* __restrict__ in,
                                             unsigned short* __restrict__ out, int n) {
    int i = (blockIdx.x * 256 + threadIdx.x) * 4;
    if (i >= n) return;
    float4 a = *reinterpret_cast<const float4*>(in + i);
    s16x4 r;
    r[0] = (short)f2bf(a.x);
    r[1] = (short)f2bf(a.y);
    r[2] = (short)f2bf(a.z);
    r[3] = (short)f2bf(a.w);
    *reinterpret_cast<s16x4*>(out + i) = r;
}

// ---------------- GEMM core: C[m,n] = sum_k A[m,k]*B[n,k], 128x128 tile, BK=64 ----------------
__device__ __forceinline__ void gemm_core(const unsigned short* __restrict__ A,
                                          const unsigned short* __restrict__ Bm,
                                          int m0, int n0, int t,
                                          unsigned short (*As)[64],
                                          unsigned short (*Bs)[64],
                                          f32x4 acc[4][4]) {
    const int lane = t & 63, w = t >> 6;
    const int wm = (w >> 1) * 64, wn = (w & 1) * 64;
    const int lo = lane & 15, hi = lane >> 4;

    for (int k0 = 0; k0 < DM; k0 += 64) {
#pragma unroll
        for (int i = 0; i < 4; i++) {
            int c = i * 256 + t;
            int r = c >> 3, col = (c & 7) * 8;
            gload16(A  + (size_t)(m0 + r) * DM + k0 + col, &As[r][col]);
            gload16(Bm + (size_t)(n0 + r) * DM + k0 + col, &Bs[r][col]);
        }
        asm volatile("s_waitcnt vmcnt(0)" ::: "memory");
        __syncthreads();

#pragma unroll
        for (int kk = 0; kk < 64; kk += 32) {
            s16x8 a[4], b[4];
#pragma unroll
            for (int mi = 0; mi < 4; mi++)
                a[mi] = *reinterpret_cast<const s16x8*>(&As[wm + mi * 16 + lo][kk + hi * 8]);
#pragma unroll
            for (int ni = 0; ni < 4; ni++)
                b[ni] = *reinterpret_cast<const s16x8*>(&Bs[wn + ni * 16 + lo][kk + hi * 8]);
#pragma unroll
            for (int mi = 0; mi < 4; mi++)
#pragma unroll
                for (int ni = 0; ni < 4; ni++)
                    acc[mi][ni] = __builtin_amdgcn_mfma_f32_16x16x32_bf16(
                        a[mi], b[ni], acc[mi][ni], 0, 0, 0);
        }
        __syncthreads();
    }
}

// ---------------- fused QKV projection: z selects {q,k,v} ----------------
// q: out = (acc+bias)*(0.125*log2(e)) -- softmax scale AND exp2-domain fold
// k: out = acc+bias, normal layout
// v: out = acc+bias written head-transposed: vt[(b*1024 + n)*SQ + l],
//    stored as s16x4 runs along l (j=0..3 are consecutive l) for 32B-chunk
//    coalescing instead of 2B scatter at 4KB stride.
__global__ __launch_bounds__(256, 3) void gemm_qkv(
    const unsigned short* __restrict__ Qb, const unsigned short* __restrict__ Kb,
    const unsigned short* __restrict__ Vb,
    const unsigned short* __restrict__ Wq, const unsigned short* __restrict__ Wk,
    const unsigned short* __restrict__ Wv,
    const float* __restrict__ bq, const float* __restrict__ bk, const float* __restrict__ bv,
    unsigned short* __restrict__ qp, unsigned short* __restrict__ kp,
    unsigned short* __restrict__ vt) {
    __shared__ __align__(16) unsigned short As[128][64];
    __shared__ __align__(16) unsigned short Bs[128][64];
    const int t = threadIdx.x;
    const int z = blockIdx.z;
    const unsigned short* A    = (z == 0) ? Qb : (z == 1) ? Kb : Vb;
    const unsigned short* Bm   = (z == 0) ? Wq : (z == 1) ? Wk : Wv;
    const float*          bias = (z == 0) ? bq : (z == 1) ? bk : bv;
    const int m0 = blockIdx.y * 128, n0 = blockIdx.x * 128;

    f32x4 acc[4][4] = {};
    gemm_core(A, Bm, m0, n0, t, As, Bs, acc);

    const int lane = t & 63, w = t >> 6;
    const int wm = (w >> 1) * 64, wn = (w & 1) * 64;
    const int lo = lane & 15, hi = lane >> 4;

    if (z < 2) {
        unsigned short* C = z ? kp : qp;
        // q-scale: 1/sqrt(64) * log2(e) so attention scores are in the exp2 domain
        const float scale = z ? 1.0f : 0.18033688011112042f;
#pragma unroll
        for (int mi = 0; mi < 4; mi++)
#pragma unroll
            for (int ni = 0; ni < 4; ni++) {
                int cc = n0 + wn + ni * 16 + lo;
                float bb = bias[cc];
#pragma unroll
                for (int j = 0; j < 4; j++) {
                    int rr = m0 + wm + mi * 16 + hi * 4 + j;
                    C[(size_t)rr * DM + cc] = f2bf((acc[mi][ni][j] + bb) * scale);
                }
            }
    } else {
#pragma unroll
        for (int mi = 0; mi < 4; mi++)
#pragma unroll
            for (int ni = 0; ni < 4; ni++) {
                int cc = n0 + wn + ni * 16 + lo;       // 0..1023 = head*64 + d
                float bb = bias[cc];
                int rr0 = m0 + wm + mi * 16 + hi * 4;  // 4-aligned; tile never straddles b
                size_t base = ((size_t)(rr0 >> 11) * DM + cc) * SQ + (rr0 & (SQ - 1));
                s16x4 st;
#pragma unroll
                for (int j = 0; j < 4; j++)
                    st[j] = (short)f2bf(acc[mi][ni][j] + bb);
                *reinterpret_cast<s16x4*>(&vt[base]) = st;
            }
    }
}

// ---------------- final projection: fp32 out + bias ----------------
__global__ __launch_bounds__(256, 3) void gemm_out(
    const unsigned short* __restrict__ Ao, const unsigned short* __restrict__ Wo,
    const float* __restrict__ bo, float* __restrict__ Cout) {
    __shared__ __align__(16) unsigned short As[128][64];
    __shared__ __align__(16) unsigned short Bs[128][64];
    const int t = threadIdx.x;
    const int m0 = blockIdx.y * 128, n0 = blockIdx.x * 128;

    f32x4 acc[4][4] = {};
    gemm_core(Ao, Wo, m0, n0, t, As, Bs, acc);

    const int lane = t & 63, w = t >> 6;
    const int wm = (w >> 1) * 64, wn = (w & 1) * 64;
    const int lo = lane & 15, hi = lane >> 4;
#pragma unroll
    for (int mi = 0; mi < 4; mi++)
#pragma unroll
        for (int ni = 0; ni < 4; ni++) {
            int cc = n0 + wn + ni * 16 + lo;
            float bb = bo[cc];
#pragma unroll
            for (int j = 0; j < 4; j++) {
                int rr = m0 + wm + mi * 16 + hi * 4 + j;
                Cout[(size_t)rr * DM + cc] = acc[mi][ni][j] + bb;
            }
        }
}

// ---------------- flash attention: swapped QK^T, 32x32 MFMA, in-register P ----------------
// grid = (SQ/128, NB*NH); block = 256 (4 waves x 32 q-rows each).
// VALU-bound per round-6 counters (VALUBusy 55, MfmaUtil 14) -> this round cuts
// softmax/pack VALU ops: cvt_pk packing (T12), max3 tree, defer-max (T13),
// multi-acc exp sum, setprio (T5), Q fragments direct to registers (Qs LDS dropped).
__global__ __launch_bounds__(256, 2) void attn_k(
    const unsigned short* __restrict__ qp, const unsigned short* __restrict__ kp,
    const unsigned short* __restrict__ vt, unsigned short* __restrict__ ao) {
    __shared__ __align__(16) unsigned short Ks[128][64];   // 8 slots/row, swz ^(row&7)
    __shared__ __align__(16) unsigned short Vs[64][128];   // 16 slots/row, swz ^(row&15)

    const int t = threadIdx.x;
    const int lane = t & 63, w = t >> 6;
    const int l5 = lane & 31, hb = lane >> 5;
    const int q0 = blockIdx.x * 128;
    const int bh = blockIdx.y;         // b*16 + h
    const int b = bh >> 4, h = bh & 15;

    // Q fragments straight from global (read once; only consumer of these rows)
    const unsigned short* qrow = qp + (size_t)(b * SQ + q0 + w * 32 + l5) * DM + h * DH;
    s16x8 qfrag[4];
#pragma unroll
    for (int kk = 0; kk < 4; kk++)
        qfrag[kk] = *reinterpret_cast<const s16x8*>(qrow + kk * 16 + hb * 8);

    float mrow = -1e30f, lrow = 0.0f;
    f32x16 oaccT[2] = {};   // O^T frags: d = dblk*32+(reg&3)+8*(reg>>2)+4*hb, q = w*32+l5

    for (int kt = 0; kt < SQ; kt += 128) {
        // stage K tile (128x64) and V tile (64x128), source columns inverse-swizzled
#pragma unroll
        for (int i = 0; i < 4; i++) {
            int c = i * 256 + t;
            int r = c >> 3, col = ((c & 7) ^ (r & 7)) * 8;
            gload16(kp + (size_t)(b * SQ + kt + r) * DM + h * DH + col, &Ks[r][(c & 7) * 8]);
        }
#pragma unroll
        for (int i = 0; i < 4; i++) {
            int c = i * 256 + t;
            int r = c >> 4, col = ((c & 15) ^ (r & 15)) * 8;
            gload16(vt + (size_t)(bh * DH + r) * SQ + kt + col, &Vs[r][(c & 15) * 8]);
        }
        asm volatile("s_waitcnt vmcnt(0)" ::: "memory");
        __syncthreads();

        // S^T = K . Q^T : sT[ks] holds k-rows ks*32+(reg&3)+8*(reg>>2)+4*hb, q-col l5
        f32x16 sT[4] = {};
        __builtin_amdgcn_s_setprio(1);
#pragma unroll
        for (int ks = 0; ks < 4; ks++) {
#pragma unroll
            for (int kk = 0; kk < 4; kk++) {
                int kr = ks * 32 + l5;
                s16x8 kf = *reinterpret_cast<const s16x8*>(
                    &Ks[kr][((kk * 2 + hb) ^ (kr & 7)) * 8]);
                sT[ks] = __builtin_amdgcn_mfma_f32_32x32x16_bf16(
                    kf, qfrag[kk], sT[ks], 0, 0, 0);
            }
        }
        __builtin_amdgcn_s_setprio(0);

        // tile max via max3-shaped tree (v_max3_f32 fusion)
        float mx = -3.0e38f;
#pragma unroll
        for (int ks = 0; ks < 4; ks++) {
            float t0 = fmaxf(fmaxf(sT[ks][0], sT[ks][1]), sT[ks][2]);
            float t1 = fmaxf(fmaxf(sT[ks][3], sT[ks][4]), sT[ks][5]);
            float t2 = fmaxf(fmaxf(sT[ks][6], sT[ks][7]), sT[ks][8]);
            float t3 = fmaxf(fmaxf(sT[ks][9], sT[ks][10]), sT[ks][11]);
            float t4 = fmaxf(fmaxf(sT[ks][12], sT[ks][13]), sT[ks][14]);
            float t5 = fmaxf(fmaxf(sT[ks][15], t0), t1);
            float t6 = fmaxf(fmaxf(t2, t3), t4);
            mx = fmaxf(fmaxf(mx, t5), t6);
        }
        mx = fmaxf(mx, __shfl_xor(mx, 32));

        // defer-max (T13): only rescale when the tile max grew past THR=8 (exp2 dom)
        if (!__all(mx <= mrow + 8.0f)) {
            float mnew = fmaxf(mrow, mx);
            float fs = exp2f(mrow - mnew);
            mrow = mnew;
            lrow *= fs;
            oaccT[0] *= fs;
            oaccT[1] *= fs;
        }

        // P = exp2(S - mrow) (bounded by 2^8); multi-accumulator sum for ILP
        float ps0 = 0.0f, ps1 = 0.0f, ps2 = 0.0f, ps3 = 0.0f;
#pragma unroll
        for (int ks = 0; ks < 4; ks++)
#pragma unroll
            for (int r = 0; r < 16; r += 4) {
                float e0 = exp2f(sT[ks][r]     - mrow);
                float e1 = exp2f(sT[ks][r + 1] - mrow);
                float e2 = exp2f(sT[ks][r + 2] - mrow);
                float e3 = exp2f(sT[ks][r + 3] - mrow);
                sT[ks][r] = e0; sT[ks][r + 1] = e1;
                sT[ks][r + 2] = e2; sT[ks][r + 3] = e3;
                ps0 += e0; ps1 += e1; ps2 += e2; ps3 += e3;
            }
        float ps = (ps0 + ps1) + (ps2 + ps3);
        ps += __shfl_xor(ps, 32);
        lrow += ps;

        // PV: O^T += V^T . P^T, P packed via v_cvt_pk_bf16_f32 + lane^32 exchange
#pragma unroll
        for (int ks = 0; ks < 4; ks++) {
            unsigned int pw0[4], pw1[4];   // pw0[m]=pack(j0,j1), pw1[m]=pack(j2,j3)
#pragma unroll
            for (int m = 0; m < 4; m++) {
                pw0[m] = cvtpk(sT[ks][4 * m], sT[ks][4 * m + 1]);
                pw1[m] = cvtpk(sT[ks][4 * m + 2], sT[ks][4 * m + 3]);
            }
#pragma unroll
            for (int tt = 0; tt < 2; tt++) {
                unsigned int s0 = hb ? pw0[2 * tt] : pw0[2 * tt + 1];
                unsigned int s1 = hb ? pw1[2 * tt] : pw1[2 * tt + 1];
                unsigned int r0 = __shfl_xor(s0, 32);
                unsigned int r1 = __shfl_xor(s1, 32);
                union { unsigned int u[4]; s16x8 v; } uu;
                if (hb == 0) { uu.u[0] = pw0[2 * tt]; uu.u[1] = pw1[2 * tt];
                               uu.u[2] = r0;          uu.u[3] = r1; }
                else         { uu.u[0] = r0;          uu.u[1] = r1;
                               uu.u[2] = pw0[2 * tt + 1]; uu.u[3] = pw1[2 * tt + 1]; }
                s16x8 pf = uu.v;
                __builtin_amdgcn_s_setprio(1);
#pragma unroll
                for (int dblk = 0; dblk < 2; dblk++) {
                    int vr = dblk * 32 + l5;
                    int sl = ((ks * 2 + tt) * 2 + hb) ^ (vr & 15);
                    s16x8 vf = *reinterpret_cast<const s16x8*>(&Vs[vr][sl * 8]);
                    oaccT[dblk] = __builtin_amdgcn_mfma_f32_32x32x16_bf16(
                        vf, pf, oaccT[dblk], 0, 0, 0);
                }
                __builtin_amdgcn_s_setprio(0);
            }
        }
        __syncthreads();
    }

    // epilogue: normalize (lane-local q) and store bf16, 8B per store
    float inv = 1.0f / lrow;
    size_t rowbase = (size_t)(b * SQ + q0 + w * 32 + l5) * DM + h * DH;
#pragma unroll
    for (int dblk = 0; dblk < 2; dblk++)
#pragma unroll
        for (int g = 0; g < 4; g++) {
            unsigned int w0 = cvtpk(oaccT[dblk][4 * g] * inv, oaccT[dblk][4 * g + 1] * inv);
            unsigned int w1 = cvtpk(oaccT[dblk][4 * g + 2] * inv, oaccT[dblk][4 * g + 3] * inv);
            uint2 st = make_uint2(w0, w1);
            *reinterpret_cast<uint2*>(&ao[rowbase + dblk * 32 + 8 * g + 4 * hb]) = st;
        }
}

extern "C" void kernel_launch(void* const* d_in, const int* in_sizes, int n_in,
                              void* d_out, int out_size, void* d_ws, size_t ws_size,
                              hipStream_t stream) {
    const float* Q  = (const float*)d_in[0];
    const float* K  = (const float*)d_in[1];
    const float* V  = (const float*)d_in[2];
    const float* Wq = (const float*)d_in[3];
    const float* bq = (const float*)d_in[4];
    const float* Wk = (const float*)d_in[5];
    const float* bk = (const float*)d_in[6];
    const float* Wv = (const float*)d_in[7];
    const float* bv = (const float*)d_in[8];
    const float* Wo = (const float*)d_in[9];
    const float* bo = (const float*)d_in[10];

    // workspace layout (all 256B-aligned); total = 64 MiB
    char* ws = (char*)d_ws;
    size_t off = 0;
    auto alloc = [&](size_t bytes) {
        void* p = ws + off;
        off += (bytes + 255) & ~(size_t)255;
        return p;
    };
    const size_t XB = (size_t)MT * DM * 2;  // 8 MiB (bf16 activation)
    const size_t WB = (size_t)DM * DM * 2;  // 2 MiB (bf16 weight)
    unsigned short* qb  = (unsigned short*)alloc(XB);
    unsigned short* kb  = (unsigned short*)alloc(XB);
    unsigned short* vb  = (unsigned short*)alloc(XB);
    unsigned short* wqb = (unsigned short*)alloc(WB);
    unsigned short* wkb = (unsigned short*)alloc(WB);
    unsigned short* wvb = (unsigned short*)alloc(WB);
    unsigned short* wob = (unsigned short*)alloc(WB);
    unsigned short* qp  = (unsigned short*)alloc(XB);
    unsigned short* kp  = (unsigned short*)alloc(XB);
    unsigned short* vtp = (unsigned short*)alloc(XB);
    unsigned short* ao  = (unsigned short*)alloc(XB);

    // 1) casts fp32 -> bf16
    castk<<<dim3(MT * DM / 1024), 256, 0, stream>>>(Q, qb, MT * DM);
    castk<<<dim3(MT * DM / 1024), 256, 0, stream>>>(K, kb, MT * DM);
    castk<<<dim3(MT * DM / 1024), 256, 0, stream>>>(V, vb, MT * DM);
    castk<<<dim3(DM * DM / 1024), 256, 0, stream>>>(Wq, wqb, DM * DM);
    castk<<<dim3(DM * DM / 1024), 256, 0, stream>>>(Wk, wkb, DM * DM);
    castk<<<dim3(DM * DM / 1024), 256, 0, stream>>>(Wv, wvb, DM * DM);
    castk<<<dim3(DM * DM / 1024), 256, 0, stream>>>(Wo, wob, DM * DM);

    // 2) fused QKV projections (z = 0/1/2 -> q/k/v)
    gemm_qkv<<<dim3(DM / 128, MT / 128, 3), 256, 0, stream>>>(
        qb, kb, vb, wqb, wkb, wvb, bq, bk, bv, qp, kp, vtp);

    // 3) flash attention
    attn_k<<<dim3(SQ / 128, NB * NH), 256, 0, stream>>>(qp, kp, vtp, ao);

    // 4) output projection (fp32 out)
    gemm_out<<<dim3(DM / 128, MT / 128), 256, 0, stream>>>(ao, wob, bo, (float*)d_out);
}

// Round 9
// 254.223 us; speedup vs baseline: 1.2595x; 1.0346x over previous
//
#include <hip/hip_runtime.h>
#include <cstdint>
#include <cstddef>

// Problem constants
#define DM 1024   // d_model
#define NH 16     // heads
#define DH 64     // d_head
#define NB 2      // batch
#define SQ 2048   // seq len
#define MT (NB*SQ) // 4096 total rows

typedef float  f32x4  __attribute__((ext_vector_type(4)));
typedef float  f32x16 __attribute__((ext_vector_type(16)));
typedef short  s16x8 __attribute__((ext_vector_type(8)));
typedef short  s16x4 __attribute__((ext_vector_type(4)));

// fp32 -> bf16 bits, round-to-nearest-even (no __hip_bfloat16 dependency)
__device__ __forceinline__ unsigned short f2bf(float x) {
    unsigned int u = __float_as_uint(x);
    unsigned int lsb = (u >> 16) & 1u;
    u += 0x7fffu + lsb;
    return (unsigned short)(u >> 16);
}

// packed fp32->bf16x2 (RNE), dst.lo16 = bf16(lo), dst.hi16 = bf16(hi)
__device__ __forceinline__ unsigned int cvtpk(float lo, float hi) {
    unsigned int r;
    asm("v_cvt_pk_bf16_f32 %0, %1, %2" : "=v"(r) : "v"(lo), "v"(hi));
    return r;
}

// async global->LDS, 16 bytes per lane (dest = wave-uniform base + lane*16)
__device__ __forceinline__ void gload16(const void* g, void* l) {
    __builtin_amdgcn_global_load_lds(
        (const __attribute__((address_space(1))) void*)g,
        (__attribute__((address_space(3))) void*)l,
        16, 0, 0);
}

// ---------------- merged cast kernel: all 7 fp32->bf16 tensors in one launch ----------------
// segments: 3 x MT*DM (Q,K,V) then 4 x DM*DM (Wq,Wk,Wv,Wo). 1024 elems/block.
#define BIGB (MT*DM/1024)   // 4096 blocks per activation tensor
#define WB_B (DM*DM/1024)   // 1024 blocks per weight tensor
__global__ __launch_bounds__(256) void castall(
    const float* __restrict__ s0, const float* __restrict__ s1, const float* __restrict__ s2,
    const float* __restrict__ s3, const float* __restrict__ s4, const float* __restrict__ s5,
    const float* __restrict__ s6,
    unsigned short* __restrict__ d0, unsigned short* __restrict__ d1,
    unsigned short* __restrict__ d2, unsigned short* __restrict__ d3,
    unsigned short* __restrict__ d4, unsigned short* __restrict__ d5,
    unsigned short* __restrict__ d6) {
    int bid = blockIdx.x;
    const float* src;
    unsigned short* dst;
    int off;
    if (bid < 3 * BIGB) {
        int seg = bid / BIGB;
        off = (bid - seg * BIGB) * 1024;
        src = (seg == 0) ? s0 : (seg == 1) ? s1 : s2;
        dst = (seg == 0) ? d0 : (seg == 1) ? d1 : d2;
    } else {
        int r = bid - 3 * BIGB;
        int seg = r / WB_B;
        off = (r - seg * WB_B) * 1024;
        src = (seg == 0) ? s3 : (seg == 1) ? s4 : (seg == 2) ? s5 : s6;
        dst = (seg == 0) ? d3 : (seg == 1) ? d4 : (seg == 2) ? d5 : d6;
    }
    int i = off + threadIdx.x * 4;
    float4 a = *reinterpret_cast<const float4*>(src + i);
    s16x4 rr;
    rr[0] = (short)f2bf(a.x);
    rr[1] = (short)f2bf(a.y);
    rr[2] = (short)f2bf(a.z);
    rr[3] = (short)f2bf(a.w);
    *reinterpret_cast<s16x4*>(dst + i) = rr;
}

// ---------------- GEMM core: C[m,n] = sum_k A[m,k]*B[n,k], 128x128 tile, BK=64 ----------------
__device__ __forceinline__ void gemm_core(const unsigned short* __restrict__ A,
                                          const unsigned short* __restrict__ Bm,
                                          int m0, int n0, int t,
                                          unsigned short (*As)[64],
                                          unsigned short (*Bs)[64],
                                          f32x4 acc[4][4]) {
    const int lane = t & 63, w = t >> 6;
    const int wm = (w >> 1) * 64, wn = (w & 1) * 64;
    const int lo = lane & 15, hi = lane >> 4;

    for (int k0 = 0; k0 < DM; k0 += 64) {
#pragma unroll
        for (int i = 0; i < 4; i++) {
            int c = i * 256 + t;
            int r = c >> 3, col = (c & 7) * 8;
            gload16(A  + (size_t)(m0 + r) * DM + k0 + col, &As[r][col]);
            gload16(Bm + (size_t)(n0 + r) * DM + k0 + col, &Bs[r][col]);
        }
        asm volatile("s_waitcnt vmcnt(0)" ::: "memory");
        __syncthreads();

#pragma unroll
        for (int kk = 0; kk < 64; kk += 32) {
            s16x8 a[4], b[4];
#pragma unroll
            for (int mi = 0; mi < 4; mi++)
                a[mi] = *reinterpret_cast<const s16x8*>(&As[wm + mi * 16 + lo][kk + hi * 8]);
#pragma unroll
            for (int ni = 0; ni < 4; ni++)
                b[ni] = *reinterpret_cast<const s16x8*>(&Bs[wn + ni * 16 + lo][kk + hi * 8]);
#pragma unroll
            for (int mi = 0; mi < 4; mi++)
#pragma unroll
                for (int ni = 0; ni < 4; ni++)
                    acc[mi][ni] = __builtin_amdgcn_mfma_f32_16x16x32_bf16(
                        a[mi], b[ni], acc[mi][ni], 0, 0, 0);
        }
        __syncthreads();
    }
}

// ---------------- fused QKV projection: z selects {q,k,v} ----------------
__global__ __launch_bounds__(256, 3) void gemm_qkv(
    const unsigned short* __restrict__ Qb, const unsigned short* __restrict__ Kb,
    const unsigned short* __restrict__ Vb,
    const unsigned short* __restrict__ Wq, const unsigned short* __restrict__ Wk,
    const unsigned short* __restrict__ Wv,
    const float* __restrict__ bq, const float* __restrict__ bk, const float* __restrict__ bv,
    unsigned short* __restrict__ qp, unsigned short* __restrict__ kp,
    unsigned short* __restrict__ vt) {
    __shared__ __align__(16) unsigned short As[128][64];
    __shared__ __align__(16) unsigned short Bs[128][64];
    const int t = threadIdx.x;
    const int z = blockIdx.z;
    const unsigned short* A    = (z == 0) ? Qb : (z == 1) ? Kb : Vb;
    const unsigned short* Bm   = (z == 0) ? Wq : (z == 1) ? Wk : Wv;
    const float*          bias = (z == 0) ? bq : (z == 1) ? bk : bv;
    const int m0 = blockIdx.y * 128, n0 = blockIdx.x * 128;

    f32x4 acc[4][4] = {};
    gemm_core(A, Bm, m0, n0, t, As, Bs, acc);

    const int lane = t & 63, w = t >> 6;
    const int wm = (w >> 1) * 64, wn = (w & 1) * 64;
    const int lo = lane & 15, hi = lane >> 4;

    if (z < 2) {
        unsigned short* C = z ? kp : qp;
        // q-scale: 1/sqrt(64) * log2(e) so attention scores are in the exp2 domain
        const float scale = z ? 1.0f : 0.18033688011112042f;
#pragma unroll
        for (int mi = 0; mi < 4; mi++)
#pragma unroll
            for (int ni = 0; ni < 4; ni++) {
                int cc = n0 + wn + ni * 16 + lo;
                float bb = bias[cc];
#pragma unroll
                for (int j = 0; j < 4; j++) {
                    int rr = m0 + wm + mi * 16 + hi * 4 + j;
                    C[(size_t)rr * DM + cc] = f2bf((acc[mi][ni][j] + bb) * scale);
                }
            }
    } else {
#pragma unroll
        for (int mi = 0; mi < 4; mi++)
#pragma unroll
            for (int ni = 0; ni < 4; ni++) {
                int cc = n0 + wn + ni * 16 + lo;       // 0..1023 = head*64 + d
                float bb = bias[cc];
                int rr0 = m0 + wm + mi * 16 + hi * 4;  // 4-aligned; tile never straddles b
                size_t base = ((size_t)(rr0 >> 11) * DM + cc) * SQ + (rr0 & (SQ - 1));
                s16x4 st;
#pragma unroll
                for (int j = 0; j < 4; j++)
                    st[j] = (short)f2bf(acc[mi][ni][j] + bb);
                *reinterpret_cast<s16x4*>(&vt[base]) = st;
            }
    }
}

// ---------------- final projection: fp32 out + bias ----------------
__global__ __launch_bounds__(256, 3) void gemm_out(
    const unsigned short* __restrict__ Ao, const unsigned short* __restrict__ Wo,
    const float* __restrict__ bo, float* __restrict__ Cout) {
    __shared__ __align__(16) unsigned short As[128][64];
    __shared__ __align__(16) unsigned short Bs[128][64];
    const int t = threadIdx.x;
    const int m0 = blockIdx.y * 128, n0 = blockIdx.x * 128;

    f32x4 acc[4][4] = {};
    gemm_core(Ao, Wo, m0, n0, t, As, Bs, acc);

    const int lane = t & 63, w = t >> 6;
    const int wm = (w >> 1) * 64, wn = (w & 1) * 64;
    const int lo = lane & 15, hi = lane >> 4;
#pragma unroll
    for (int mi = 0; mi < 4; mi++)
#pragma unroll
        for (int ni = 0; ni < 4; ni++) {
            int cc = n0 + wn + ni * 16 + lo;
            float bb = bo[cc];
#pragma unroll
            for (int j = 0; j < 4; j++) {
                int rr = m0 + wm + mi * 16 + hi * 4 + j;
                Cout[(size_t)rr * DM + cc] = acc[mi][ni][j] + bb;
            }
        }
}

// ---------------- flash attention: dbuf K/V staging (T3+T4), swapped QK^T ----------------
// grid = (SQ/128, NB*NH); block = 256 (4 waves x 32 q-rows each).
// Round-8 counters: VALU 54, Mfma 17 -> ~29% stall from serial stage->vmcnt(0)->
// barrier per tile. Fix: double-buffered K/V LDS; issue next tile's 8
// global_load_lds FIRST, then s_waitcnt vmcnt(8) (current tile's loads landed,
// next tile's stay IN FLIGHT across raw s_barrier - NOT __syncthreads, which
// drains vmcnt to 0). Second barrier after compute protects the buffer being
// restaged next iteration. sched_barrier(0) pins code motion (rule #18).
__global__ __launch_bounds__(256, 2) void attn_k(
    const unsigned short* __restrict__ qp, const unsigned short* __restrict__ kp,
    const unsigned short* __restrict__ vt, unsigned short* __restrict__ ao) {
    __shared__ __align__(16) unsigned short Ks[2][128][64];   // swz ^(row&7)
    __shared__ __align__(16) unsigned short Vs[2][64][128];   // swz ^(row&15)

    const int t = threadIdx.x;
    const int lane = t & 63, w = t >> 6;
    const int l5 = lane & 31, hb = lane >> 5;
    const int q0 = blockIdx.x * 128;
    const int bh = blockIdx.y;         // b*16 + h
    const int b = bh >> 4, h = bh & 15;

    // Q fragments straight from global (read once; only consumer of these rows)
    const unsigned short* qrow = qp + (size_t)(b * SQ + q0 + w * 32 + l5) * DM + h * DH;
    s16x8 qfrag[4];
#pragma unroll
    for (int kk = 0; kk < 4; kk++)
        qfrag[kk] = *reinterpret_cast<const s16x8*>(qrow + kk * 16 + hb * 8);

    // stage K tile (128x64) + V tile (64x128) into buffer bufi, 8 gload16/thread
    auto stage = [&](int bufi, int kt) {
#pragma unroll
        for (int i = 0; i < 4; i++) {
            int c = i * 256 + t;
            int r = c >> 3, col = ((c & 7) ^ (r & 7)) * 8;
            gload16(kp + (size_t)(b * SQ + kt + r) * DM + h * DH + col,
                    &Ks[bufi][r][(c & 7) * 8]);
        }
#pragma unroll
        for (int i = 0; i < 4; i++) {
            int c = i * 256 + t;
            int r = c >> 4, col = ((c & 15) ^ (r & 15)) * 8;
            gload16(vt + (size_t)(bh * DH + r) * SQ + kt + col,
                    &Vs[bufi][r][(c & 15) * 8]);
        }
    };

    float mrow = -1e30f, lrow = 0.0f;
    f32x16 oaccT[2] = {};   // O^T frags: d = dblk*32+(reg&3)+8*(reg>>2)+4*hb, q = w*32+l5

    stage(0, 0);            // prologue: tile 0 into buf 0
    int cur = 0;
    const int NT = SQ / 128;

    for (int ti = 0; ti < NT; ti++) {
        if (ti + 1 < NT) {
            stage(cur ^ 1, (ti + 1) * 128);                      // issue next tile early
            asm volatile("s_waitcnt vmcnt(8)" ::: "memory");     // current tile landed
        } else {
            asm volatile("s_waitcnt vmcnt(0)" ::: "memory");     // tail: drain all
        }
        __builtin_amdgcn_sched_barrier(0);
        __builtin_amdgcn_s_barrier();   // all waves' tile-ti data visible (raw: keeps loads in flight)

        // S^T = K . Q^T : sT[ks] holds k-rows ks*32+(reg&3)+8*(reg>>2)+4*hb, q-col l5
        f32x16 sT[4] = {};
        __builtin_amdgcn_s_setprio(1);
#pragma unroll
        for (int ks = 0; ks < 4; ks++) {
#pragma unroll
            for (int kk = 0; kk < 4; kk++) {
                int kr = ks * 32 + l5;
                s16x8 kf = *reinterpret_cast<const s16x8*>(
                    &Ks[cur][kr][((kk * 2 + hb) ^ (kr & 7)) * 8]);
                sT[ks] = __builtin_amdgcn_mfma_f32_32x32x16_bf16(
                    kf, qfrag[kk], sT[ks], 0, 0, 0);
            }
        }
        __builtin_amdgcn_s_setprio(0);

        // tile max via max3-shaped tree (v_max3_f32 fusion)
        float mx = -3.0e38f;
#pragma unroll
        for (int ks = 0; ks < 4; ks++) {
            float t0 = fmaxf(fmaxf(sT[ks][0], sT[ks][1]), sT[ks][2]);
            float t1 = fmaxf(fmaxf(sT[ks][3], sT[ks][4]), sT[ks][5]);
            float t2 = fmaxf(fmaxf(sT[ks][6], sT[ks][7]), sT[ks][8]);
            float t3 = fmaxf(fmaxf(sT[ks][9], sT[ks][10]), sT[ks][11]);
            float t4 = fmaxf(fmaxf(sT[ks][12], sT[ks][13]), sT[ks][14]);
            float t5 = fmaxf(fmaxf(sT[ks][15], t0), t1);
            float t6 = fmaxf(fmaxf(t2, t3), t4);
            mx = fmaxf(fmaxf(mx, t5), t6);
        }
        mx = fmaxf(mx, __shfl_xor(mx, 32));

        // defer-max (T13): only rescale when the tile max grew past THR=8 (exp2 dom)
        if (!__all(mx <= mrow + 8.0f)) {
            float mnew = fmaxf(mrow, mx);
            float fs = exp2f(mrow - mnew);
            mrow = mnew;
            lrow *= fs;
            oaccT[0] *= fs;
            oaccT[1] *= fs;
        }

        // P = exp2(S - mrow) (bounded by 2^8); multi-accumulator sum for ILP
        float ps0 = 0.0f, ps1 = 0.0f, ps2 = 0.0f, ps3 = 0.0f;
#pragma unroll
        for (int ks = 0; ks < 4; ks++)
#pragma unroll
            for (int r = 0; r < 16; r += 4) {
                float e0 = exp2f(sT[ks][r]     - mrow);
                float e1 = exp2f(sT[ks][r + 1] - mrow);
                float e2 = exp2f(sT[ks][r + 2] - mrow);
                float e3 = exp2f(sT[ks][r + 3] - mrow);
                sT[ks][r] = e0; sT[ks][r + 1] = e1;
                sT[ks][r + 2] = e2; sT[ks][r + 3] = e3;
                ps0 += e0; ps1 += e1; ps2 += e2; ps3 += e3;
            }
        float ps = (ps0 + ps1) + (ps2 + ps3);
        ps += __shfl_xor(ps, 32);
        lrow += ps;

        // PV: O^T += V^T . P^T, P packed via v_cvt_pk_bf16_f32 + lane^32 exchange
#pragma unroll
        for (int ks = 0; ks < 4; ks++) {
            unsigned int pw0[4], pw1[4];   // pw0[m]=pack(j0,j1), pw1[m]=pack(j2,j3)
#pragma unroll
            for (int m = 0; m < 4; m++) {
                pw0[m] = cvtpk(sT[ks][4 * m], sT[ks][4 * m + 1]);
                pw1[m] = cvtpk(sT[ks][4 * m + 2], sT[ks][4 * m + 3]);
            }
#pragma unroll
            for (int tt = 0; tt < 2; tt++) {
                unsigned int s0 = hb ? pw0[2 * tt] : pw0[2 * tt + 1];
                unsigned int s1 = hb ? pw1[2 * tt] : pw1[2 * tt + 1];
                unsigned int r0 = __shfl_xor(s0, 32);
                unsigned int r1 = __shfl_xor(s1, 32);
                union { unsigned int u[4]; s16x8 v; } uu;
                if (hb == 0) { uu.u[0] = pw0[2 * tt]; uu.u[1] = pw1[2 * tt];
                               uu.u[2] = r0;          uu.u[3] = r1; }
                else         { uu.u[0] = r0;          uu.u[1] = r1;
                               uu.u[2] = pw0[2 * tt + 1]; uu.u[3] = pw1[2 * tt + 1]; }
                s16x8 pf = uu.v;
                __builtin_amdgcn_s_setprio(1);
#pragma unroll
                for (int dblk = 0; dblk < 2; dblk++) {
                    int vr = dblk * 32 + l5;
                    int sl = ((ks * 2 + tt) * 2 + hb) ^ (vr & 15);
                    s16x8 vf = *reinterpret_cast<const s16x8*>(&Vs[cur][vr][sl * 8]);
                    oaccT[dblk] = __builtin_amdgcn_mfma_f32_32x32x16_bf16(
                        vf, pf, oaccT[dblk], 0, 0, 0);
                }
                __builtin_amdgcn_s_setprio(0);
            }
        }

        __builtin_amdgcn_s_barrier();   // all reads of buf[cur] done before it is restaged
        cur ^= 1;
    }

    // epilogue: normalize (lane-local q) and store bf16, 8B per store
    float inv = 1.0f / lrow;
    size_t rowbase = (size_t)(b * SQ + q0 + w * 32 + l5) * DM + h * DH;
#pragma unroll
    for (int dblk = 0; dblk < 2; dblk++)
#pragma unroll
        for (int g = 0; g < 4; g++) {
            unsigned int w0 = cvtpk(oaccT[dblk][4 * g] * inv, oaccT[dblk][4 * g + 1] * inv);
            unsigned int w1 = cvtpk(oaccT[dblk][4 * g + 2] * inv, oaccT[dblk][4 * g + 3] * inv);
            uint2 st = make_uint2(w0, w1);
            *reinterpret_cast<uint2*>(&ao[rowbase + dblk * 32 + 8 * g + 4 * hb]) = st;
        }
}

extern "C" void kernel_launch(void* const* d_in, const int* in_sizes, int n_in,
                              void* d_out, int out_size, void* d_ws, size_t ws_size,
                              hipStream_t stream) {
    const float* Q  = (const float*)d_in[0];
    const float* K  = (const float*)d_in[1];
    const float* V  = (const float*)d_in[2];
    const float* Wq = (const float*)d_in[3];
    const float* bq = (const float*)d_in[4];
    const float* Wk = (const float*)d_in[5];
    const float* bk = (const float*)d_in[6];
    const float* Wv = (const float*)d_in[7];
    const float* bv = (const float*)d_in[8];
    const float* Wo = (const float*)d_in[9];
    const float* bo = (const float*)d_in[10];

    // workspace layout (all 256B-aligned); total = 64 MiB
    char* ws = (char*)d_ws;
    size_t off = 0;
    auto alloc = [&](size_t bytes) {
        void* p = ws + off;
        off += (bytes + 255) & ~(size_t)255;
        return p;
    };
    const size_t XB = (size_t)MT * DM * 2;  // 8 MiB (bf16 activation)
    const size_t WB = (size_t)DM * DM * 2;  // 2 MiB (bf16 weight)
    unsigned short* qb  = (unsigned short*)alloc(XB);
    unsigned short* kb  = (unsigned short*)alloc(XB);
    unsigned short* vb  = (unsigned short*)alloc(XB);
    unsigned short* wqb = (unsigned short*)alloc(WB);
    unsigned short* wkb = (unsigned short*)alloc(WB);
    unsigned short* wvb = (unsigned short*)alloc(WB);
    unsigned short* wob = (unsigned short*)alloc(WB);
    unsigned short* qp  = (unsigned short*)alloc(XB);
    unsigned short* kp  = (unsigned short*)alloc(XB);
    unsigned short* vtp = (unsigned short*)alloc(XB);
    unsigned short* ao  = (unsigned short*)alloc(XB);

    // 1) all fp32->bf16 casts in one launch
    castall<<<dim3(3 * BIGB + 4 * WB_B), 256, 0, stream>>>(
        Q, K, V, Wq, Wk, Wv, Wo, qb, kb, vb, wqb, wkb, wvb, wob);

    // 2) fused QKV projections (z = 0/1/2 -> q/k/v)
    gemm_qkv<<<dim3(DM / 128, MT / 128, 3), 256, 0, stream>>>(
        qb, kb, vb, wqb, wkb, wvb, bq, bk, bv, qp, kp, vtp);

    // 3) flash attention
    attn_k<<<dim3(SQ / 128, NB * NH), 256, 0, stream>>>(qp, kp, vtp, ao);

    // 4) output projection (fp32 out)
    gemm_out<<<dim3(DM / 128, MT / 128), 256, 0, stream>>>(ao, wob, bo, (float*)d_out);
}